// Round 5
// baseline (348.343 us; speedup 1.0000x reference)
//
#include <hip/hip_runtime.h>
#include <hip/hip_bf16.h>

// DecoderRNN: B=64, S=32, T=31 decode steps, E=D=512, V=10000
// Pipeline: k_prep(+wlstm) -> k_xproj -> k_rec (persistent, tagged-data sync) -> k_cls

typedef __attribute__((ext_vector_type(4))) float f32x4;
typedef __attribute__((ext_vector_type(8))) short short8;
typedef __attribute__((ext_vector_type(4))) unsigned short u16x4;
typedef __attribute__((ext_vector_type(4))) unsigned u32x4;

#define BB 64
#define SS 32
#define TT 31
#define EE 512
#define VV 10000

__device__ __forceinline__ float sigf(float x){ return 1.0f/(1.0f + __expf(-x)); }
__device__ __forceinline__ float tanh_(float x){
  x = fminf(15.f, fmaxf(-15.f, x));
  float e = __expf(2.f*x);
  return (e-1.f)/(e+1.f);
}
__device__ __forceinline__ unsigned short f2bf(float x){
  __hip_bfloat16 h = __float2bfloat16(x);
  return __builtin_bit_cast(unsigned short, h);
}
// Coherent (MALL-visible) memops. Caller must s_waitcnt vmcnt before using results.
__device__ __forceinline__ unsigned ld_tag(const void* p){
  unsigned r;
  asm volatile("global_load_dword %0, %1, off sc0 sc1" : "=v"(r) : "v"(p) : "memory");
  return r;
}
__device__ __forceinline__ unsigned long long ld_dat(const void* p){
  unsigned long long r;
  asm volatile("global_load_dwordx2 %0, %1, off sc0 sc1" : "=v"(r) : "v"(p) : "memory");
  return r;
}
__device__ __forceinline__ void st_ent(void* p, unsigned long long data, unsigned tag){
  u32x4 q; q.x = (unsigned)data; q.y = (unsigned)(data >> 32); q.z = tag; q.w = tag;
  asm volatile("global_store_dwordx4 %0, %1, off sc0 sc1" :: "v"(p), "v"(q) : "memory");
}

// Exchange entry: 16 B = {u64 data (4 bf16, d-consecutive), u32 tag, u32 pad}
// ex[2][64][128] entries = 262144 B. Entry(buf,b,p) at buf*131072 + b*2048 + p*16.

// ---------------------------------------------------------------------------
// Kernel 1: bf16 conversions + gathered Xa + h0-entries + tag init,
// plus (blocks >= NPREP) the hidden-size-1 "w" LSTM + dl.
// ---------------------------------------------------------------------------
#define NPREP 2048
__global__ __launch_bounds__(256) void k_prep(
    const float* __restrict__ dwih, const float* __restrict__ dwhh,
    const float* __restrict__ emb, const int* __restrict__ cap,
    const float* __restrict__ enc,
    __hip_bfloat16* __restrict__ wihbf, __hip_bfloat16* __restrict__ whhbf,
    __hip_bfloat16* __restrict__ xa, char* __restrict__ exb,
    const int* __restrict__ caplen,
    const float* __restrict__ wwih, const float* __restrict__ wwhh,
    const float* __restrict__ wbih, const float* __restrict__ wbhh,
    const float* __restrict__ ihw, const float* __restrict__ ihb,
    const float* __restrict__ icw, const float* __restrict__ icb,
    float* __restrict__ wgt, float* __restrict__ dl_out)
{
  if (blockIdx.x >= NPREP){
    // ---- w-LSTM block for batch row b ----
    int b = blockIdx.x - NPREP;
    int w = threadIdx.x >> 6, lane = threadIdx.x & 63;
    __shared__ float sv[6];   // ew[0..3], wh0, wc0

    float p = 0.f;
    for (int k = lane; k < EE; k += 64) p += enc[b*EE + k] * wwih[w*EE + k];
    #pragma unroll
    for (int off = 32; off; off >>= 1) p += __shfl_down(p, off, 64);
    if (lane == 0) sv[w] = p;

    if (w < 2){
      const float* iw = (w == 0) ? ihw : icw;
      float q = 0.f;
      for (int k = lane; k < EE; k += 64) q += enc[b*EE + k] * iw[k];
      #pragma unroll
      for (int off = 32; off; off >>= 1) q += __shfl_down(q, off, 64);
      if (lane == 0) sv[4 + w] = q + ((w == 0) ? ihb[0] : icb[0]);
    }
    __syncthreads();

    if (threadIdx.x == 0){
      float wh = sv[4], wc = sv[5];
      int dl = caplen[b] - 1;
      for (int t = 0; t < TT; t++){
        float gi = sv[0] + wh*wwhh[0] + wbih[0] + wbhh[0];
        float gf = sv[1] + wh*wwhh[1] + wbih[1] + wbhh[1];
        float gg = sv[2] + wh*wwhh[2] + wbih[2] + wbhh[2];
        float go = sv[3] + wh*wwhh[3] + wbih[3] + wbhh[3];
        float wc2 = sigf(gf)*wc + sigf(gi)*tanh_(gg);
        float wh2 = sigf(go)*tanh_(wc2);
        float m = (dl > t) ? 1.f : 0.f;
        wgt[b*TT + t] = sigf(wh2) * m;
        if (dl > t){ wh = wh2; wc = wc2; }
      }
      dl_out[b] = (float)dl;
    }
    return;
  }

  // ---- conversion / init blocks ----
  const int c1 = 2097152;              // dec_wih [2048][1024]
  const int c2 = c1 + 1048576;         // dec_whh [2048][512]
  const int c3 = c2 + 2031616;         // Xa      [1984][1024] (row r = t*64+b)
  const int c4 = c3 + 32768;           // h0 data u16 writes (64x512)
  const int c5 = c4 + 16384;           // tag init: 2 bufs x 8192 entries
  for (int i = blockIdx.x*blockDim.x + threadIdx.x; i < c5; i += NPREP*256){
    if (i < c1){ wihbf[i] = __float2bfloat16(dwih[i]); }
    else if (i < c2){ int j = i - c1; whhbf[j] = __float2bfloat16(dwhh[j]); }
    else if (i < c3){
      int j = i - c2; int r = j >> 10, k = j & 1023, t = r >> 6, b = r & 63;
      float v = (k < 512) ? emb[(size_t)cap[b*SS + t]*EE + k] : enc[b*EE + (k - 512)];
      xa[j] = __float2bfloat16(v);
    } else if (i < c4){
      int j = i - c3; int b = j >> 9, d = j & 511;
      *(unsigned short*)(exb + (size_t)b*2048 + (d >> 2)*16 + (d & 3)*2)
          = f2bf(enc[b*EE + d]);
    } else {
      int e = i - c4; int buf = e >> 13, idx = e & 8191;
      *(unsigned*)(exb + (size_t)buf*131072 + (size_t)idx*16 + 8)
          = buf ? 0xFFFFFFFFu : 0u;
    }
  }
}

// ---------------------------------------------------------------------------
// Kernel 2: x-projection GEMM: Xp[r][n] = Xa[r] . wih[n] + bih[n] + bhh[n]
// ---------------------------------------------------------------------------
__global__ __launch_bounds__(256) void k_xproj(
    const __hip_bfloat16* __restrict__ xa, const __hip_bfloat16* __restrict__ wihbf,
    const float* __restrict__ bih, const float* __restrict__ bhh,
    float* __restrict__ xp)
{
  int bm = blockIdx.y;                 // 0..30
  int bn = blockIdx.x;                 // 0..7
  int w = threadIdx.x >> 6, lane = threadIdx.x & 63;
  int col = lane & 15, kg = lane >> 4;
  int m0 = bm*64;
  int n0 = bn*256 + w*64;

  f32x4 acc[4][4] = {};
  for (int kk = 0; kk < 32; kk++){
    short8 a[4], bfr[4];
    #pragma unroll
    for (int i = 0; i < 4; i++){
      a[i]   = *(const short8*)(xa    + (size_t)(m0 + i*16 + col)*1024 + kk*32 + kg*8);
      bfr[i] = *(const short8*)(wihbf + (size_t)(n0 + i*16 + col)*1024 + kk*32 + kg*8);
    }
    #pragma unroll
    for (int mt = 0; mt < 4; mt++)
      #pragma unroll
      for (int nt = 0; nt < 4; nt++)
        acc[mt][nt] = __builtin_amdgcn_mfma_f32_16x16x32_bf16(a[mt], bfr[nt], acc[mt][nt], 0, 0, 0);
  }
  float badd[4]; int ncol[4];
  #pragma unroll
  for (int nt = 0; nt < 4; nt++){ int n = n0 + nt*16 + col; ncol[nt] = n; badd[nt] = bih[n] + bhh[n]; }
  #pragma unroll
  for (int mt = 0; mt < 4; mt++)
    #pragma unroll
    for (int rg = 0; rg < 4; rg++){
      int r = m0 + mt*16 + 4*kg + rg;
      #pragma unroll
      for (int nt = 0; nt < 4; nt++)
        xp[(size_t)r*2048 + ncol[nt]] = acc[mt][nt][rg] + badd[nt];
    }
}

// ---------------------------------------------------------------------------
// Kernel 3: persistent recurrence (blocks 0..127, 1 wave each) + fused
// cls_w->bf16 conversion (blocks 128..511).
// Sync: tag-embedded 16B exchange entries, single MALL hop per step.
// Consumer: poll 32 tags of exactly the entries it reads, then load data.
// ---------------------------------------------------------------------------
__global__ __launch_bounds__(64, 1) void k_rec(
    const __hip_bfloat16* __restrict__ whhbf,   // [2048][512]
    const float* __restrict__ xp,               // [T*64][2048]
    const float* __restrict__ enc,              // [64][512]
    const int* __restrict__ caplen,
    char* __restrict__ ex,                      // exchange buffer (262144 B)
    __hip_bfloat16* __restrict__ hout,          // [64][T][512]
    const float* __restrict__ clsw,
    __hip_bfloat16* __restrict__ clsbf)
{
  const int bid = blockIdx.x;
  const int lane = threadIdx.x;

  if (bid >= 128){                     // ---- converter blocks ----
    const int n4 = 1280000;            // 5,120,000 / 4
    for (int i = (bid - 128)*64 + lane; i < n4; i += 384*64){
      f32x4 v = ((const f32x4*)clsw)[i];
      u16x4 o;
      o.x = f2bf(v.x); o.y = f2bf(v.y); o.z = f2bf(v.z); o.w = f2bf(v.w);
      ((u16x4*)clsbf)[i] = o;
    }
    return;
  }

  // ---- recurrence ----
  const int g = bid >> 5, s = bid & 31;
  const int col = lane & 15, kg = lane >> 4;
  const int d0 = s*16;
  const int b  = g*16 + col;           // this lane's batch row
  const int dbase = d0 + 4*kg;         // 4 consecutive d owned by this lane
  const int pme = (dbase >> 2);        // my entry index within row b

  // Persistent A fragments: Whh rows {q*512 + d0 + col}, K=512 (256 VGPRs)
  short8 Aq[4][16];
  #pragma unroll
  for (int q = 0; q < 4; q++){
    const __hip_bfloat16* wrow = whhbf + (size_t)(q*512 + d0 + col)*512;
    #pragma unroll
    for (int kk = 0; kk < 16; kk++)
      Aq[q][kk] = *(const short8*)(wrow + kk*32 + kg*8);
  }
  #pragma unroll
  for (int q = 0; q < 4; q++)
    #pragma unroll
    for (int kk = 0; kk < 16; kk++)
      asm volatile("" : "+v"(Aq[q][kk]));   // pin in VGPRs

  float hst[4], cst[4];
  #pragma unroll
  for (int j = 0; j < 4; j++){
    float e = enc[(size_t)b*EE + dbase + j];
    hst[j] = e; cst[j] = e;
  }
  const int dl = caplen[b] - 1;

  f32x4 xg[4];
  #pragma unroll
  for (int q = 0; q < 4; q++)
    xg[q] = *(const f32x4*)(xp + (size_t)b*2048 + q*512 + dbase);

  for (int t = 0; t < TT; t++){
    const char* rbase = ex + (size_t)(t & 1)*131072 + (size_t)b*2048;

    // ---- spin on the 32 tags this lane will consume ----
    {
      const unsigned tagv = (unsigned)t;
      while (1){
        unsigned tg[32];
        #pragma unroll
        for (int kk = 0; kk < 16; kk++){
          int p0 = kk*8 + kg*2;
          tg[2*kk]   = ld_tag(rbase + (size_t)p0*16 + 8);
          tg[2*kk+1] = ld_tag(rbase + (size_t)(p0 + 1)*16 + 8);
        }
        asm volatile("s_waitcnt vmcnt(0)" ::: "memory");
        __builtin_amdgcn_sched_barrier(0);
        unsigned bad = 0;
        #pragma unroll
        for (int i = 0; i < 32; i++) bad |= (tg[i] ^ tagv);
        if (__all(bad == 0)) break;
      }
    }

    // ---- load data u64s (fresh: same 16B entries whose tags matched) ----
    unsigned long long dat[32];
    #pragma unroll
    for (int kk = 0; kk < 16; kk++){
      int p0 = kk*8 + kg*2;
      dat[2*kk]   = ld_dat(rbase + (size_t)p0*16);
      dat[2*kk+1] = ld_dat(rbase + (size_t)(p0 + 1)*16);
    }

    // prefetch next step's gate projections (overlaps load latency)
    f32x4 xgn[4];
    if (t + 1 < TT){
      #pragma unroll
      for (int q = 0; q < 4; q++)
        xgn[q] = *(const f32x4*)(xp + (size_t)((t+1)*BB + b)*2048 + q*512 + dbase);
    }

    asm volatile("s_waitcnt vmcnt(0)" ::: "memory");
    __builtin_amdgcn_sched_barrier(0);

    f32x4 acc[4] = {};
    #pragma unroll
    for (int kk = 0; kk < 16; kk++){
      union { unsigned long long u[2]; short8 v; } pk;
      pk.u[0] = dat[2*kk]; pk.u[1] = dat[2*kk+1];
      #pragma unroll
      for (int q = 0; q < 4; q++)
        acc[q] = __builtin_amdgcn_mfma_f32_16x16x32_bf16(Aq[q][kk], pk.v, acc[q], 0, 0, 0);
    }

    const bool act = dl > t;
    unsigned long long hpack = 0, spack = 0;
    #pragma unroll
    for (int j = 0; j < 4; j++){
      float gi = acc[0][j] + xg[0][j];
      float gf = acc[1][j] + xg[1][j];
      float gg = acc[2][j] + xg[2][j];
      float go = acc[3][j] + xg[3][j];
      float c2 = sigf(gf)*cst[j] + sigf(gi)*tanh_(gg);
      float h2 = sigf(go)*tanh_(c2);
      if (act){ cst[j] = c2; hst[j] = h2; }
      hpack |= (unsigned long long)f2bf(h2)     << (16*j);
      spack |= (unsigned long long)f2bf(hst[j]) << (16*j);
    }

    ((unsigned long long*)hout)[((size_t)b*TT + t)*128 + pme] = hpack;

    if (t < TT - 1){
      // fire-and-forget: data + tag in one 16B store, no drain, no flag
      st_ent(ex + (size_t)((t + 1) & 1)*131072 + (size_t)b*2048 + (size_t)pme*16,
             spack, (unsigned)(t + 1));
    }

    #pragma unroll
    for (int q = 0; q < 4; q++) xg[q] = xgn[q];
  }
}

// ---------------------------------------------------------------------------
// Kernel 4: classifier GEMM fused with mask + weights broadcast.
// ---------------------------------------------------------------------------
__global__ __launch_bounds__(256) void k_cls(
    const __hip_bfloat16* __restrict__ hbf,   // [1984][512] (row r = b*31+t)
    const __hip_bfloat16* __restrict__ wbf,   // [10000][512]
    const float* __restrict__ clsb,
    const float* __restrict__ wgt,            // [1984], ==0 iff masked
    float* __restrict__ preds, float* __restrict__ wout)
{
  int bid = blockIdx.x;
  int bn = bid % 79, bm = bid / 79;
  int w = threadIdx.x >> 6, lane = threadIdx.x & 63;
  int col = lane & 15, kg = lane >> 4;
  int m0 = bm*128 + (w >> 1)*64;
  int n0 = bn*128 + (w & 1)*64;
  if (m0 >= 1984) return;

  int arow[4], brow[4];
  #pragma unroll
  for (int i = 0; i < 4; i++){
    arow[i] = min(m0 + i*16 + col, 1983);
    brow[i] = min(n0 + i*16 + col, 9999);
  }
  f32x4 acc[4][4] = {};
  for (int kk = 0; kk < 16; kk++){
    short8 a[4], b[4];
    #pragma unroll
    for (int i = 0; i < 4; i++){
      a[i] = *(const short8*)(hbf + (size_t)arow[i]*512 + kk*32 + kg*8);
      b[i] = *(const short8*)(wbf + (size_t)brow[i]*512 + kk*32 + kg*8);
    }
    #pragma unroll
    for (int mt = 0; mt < 4; mt++)
      #pragma unroll
      for (int nt = 0; nt < 4; nt++)
        acc[mt][nt] = __builtin_amdgcn_mfma_f32_16x16x32_bf16(a[mt], b[nt], acc[mt][nt], 0, 0, 0);
  }
  float cb[4]; int vcol[4]; bool vok[4];
  #pragma unroll
  for (int nt = 0; nt < 4; nt++){
    int v = n0 + nt*16 + col; vcol[nt] = v; vok[nt] = (v < VV);
    cb[nt] = vok[nt] ? clsb[v] : 0.f;
  }
  #pragma unroll
  for (int mt = 0; mt < 4; mt++)
    #pragma unroll
    for (int rg = 0; rg < 4; rg++){
      int r = m0 + mt*16 + 4*kg + rg;
      if (r >= 1984) continue;
      float wv = wgt[r];
      float mf = (wv > 0.f) ? 1.f : 0.f;
      size_t base = (size_t)r*VV;
      #pragma unroll
      for (int nt = 0; nt < 4; nt++){
        if (!vok[nt]) continue;
        preds[base + vcol[nt]] = (acc[mt][nt][rg] + cb[nt]) * mf;
        wout [base + vcol[nt]] = wv;
      }
    }
}

// ---------------------------------------------------------------------------
extern "C" void kernel_launch(void* const* d_in, const int* in_sizes, int n_in,
                              void* d_out, int out_size, void* d_ws, size_t ws_size,
                              hipStream_t stream) {
  const float* enc    = (const float*)d_in[0];
  const int*   cap    = (const int*)  d_in[1];
  const int*   caplen = (const int*)  d_in[2];
  const float* emb    = (const float*)d_in[3];
  const float* dwih   = (const float*)d_in[4];
  const float* dwhh   = (const float*)d_in[5];
  const float* dbih   = (const float*)d_in[6];
  const float* dbhh   = (const float*)d_in[7];
  const float* wwih   = (const float*)d_in[8];
  const float* wwhh   = (const float*)d_in[9];
  const float* wbih   = (const float*)d_in[10];
  const float* wbhh   = (const float*)d_in[11];
  const float* ihw    = (const float*)d_in[12];
  const float* ihb    = (const float*)d_in[13];
  const float* icw    = (const float*)d_in[14];
  const float* icb    = (const float*)d_in[15];
  const float* clsw   = (const float*)d_in[16];
  const float* clsb   = (const float*)d_in[17];

  float* preds  = (float*)d_out;                       // [64][31][10000]
  float* dl_out = preds + (size_t)BB*TT*VV;            // [64]
  float* wout   = dl_out + BB;                         // [64][31][10000]

  char* ws = (char*)d_ws;
  float*          wgt   = (float*)         (ws + 0);          // 1984 f32 (pad 8192)
  char*           ex    = (char*)          (ws + 8192);       //   262,144 B exchange
  __hip_bfloat16* clsbf = (__hip_bfloat16*)(ws + 270336);     // 10,240,000 B
  __hip_bfloat16* wihbf = (__hip_bfloat16*)(ws + 10510336);   //  4,194,304 B
  __hip_bfloat16* whhbf = (__hip_bfloat16*)(ws + 14704640);   //  2,097,152 B
  __hip_bfloat16* xa    = (__hip_bfloat16*)(ws + 16801792);   //  4,063,232 B
  float*          xp    = (float*)         (ws + 20865024);   // 16,252,928 B
  __hip_bfloat16* hout  = (__hip_bfloat16*)(ws + 37117952);   //  2,031,616 B
  // total ~39.1 MB of d_ws

  k_prep <<<NPREP + BB, 256, 0, stream>>>(dwih, dwhh, emb, cap, enc,
                                          wihbf, whhbf, xa, ex,
                                          caplen, wwih, wwhh, wbih, wbhh,
                                          ihw, ihb, icw, icb, wgt, dl_out);
  k_xproj<<<dim3(8, 31), 256, 0, stream>>>(xa, wihbf, dbih, dbhh, xp);
  k_rec  <<<512, 64, 0, stream>>>(whhbf, xp, enc, caplen, ex, hout,
                                  clsw, clsbf);
  k_cls  <<<16*79, 256, 0, stream>>>(hout, clsbf, clsb, wgt, preds, wout);
}